// Round 11
// baseline (73.349 us; speedup 1.0000x reference)
//
#include <hip/hip_runtime.h>

// SoftHistLoss: x,y [16,3,512,512] f32 -> scalar f32, SINGLE fused kernel.
// hist_i = A[i] - B[i] + B[i-1] + (C[i+1] - A[i+1]); A=sum qa/255, B=sum qb/62,
// C=count, accumulated at bin k=floor(10v) as ONE packed ds_add_u32:
//   bits[31:18] qa  (col sum <= 64*255 = 16320 < 2^14)
//   bits[17: 7] qb  (col sum <= 64*31  = 1984  < 2^11)
//   bits[ 6: 0] 1   (col sum <= 64            < 2^7)
// Single-sigmoid form (R10): m = 0.5-|d-0.5|, s = sigma(-15m) = 1/(1+e^{15m}):
//   d<0.5: qa = 255-trunc(255s), qb = 0;   d>=0.5: qa = 255, qb = trunc(62s)
// -> pk = BASE + (trunc(s*scale) << sel), scale/sel cndmask'd, BASE=(255<<18)+1.
// R11: loss fused via last-block counter (R9-proven epilogue) -> 2 dispatches
// total (4-byte-class memset + fused kernel), no separate loss launch.
// Lessons carried: no FP atomics on LDS (R2), no dependent LDS reads in the
// pixel loop (R9), 1536 blocks = one occupancy round (R7).

static constexpr int PLANES   = 48;               // 16*3 per image
static constexpr int PLANE_PX = 512 * 512;
static constexpr int SPP      = 16;               // sub-blocks per plane
static constexpr int THREADS  = 256;
static constexpr int CHUNK    = PLANE_PX / SPP;   // 16384 px/block, 64 px/thread
static constexpr int NBLK     = 96 * SPP;         // 1536 = 6 blocks/CU, one round
static constexpr int CTR      = 2880;             // counter word index in G
static constexpr unsigned BASE = (255u << 18) + 1u;

__global__ __launch_bounds__(THREADS, 6) void soft_hist_fused(
    const float* __restrict__ xin, const float* __restrict__ yin,
    unsigned* __restrict__ G /* [96][30] + counter @2880 */,
    float* __restrict__ out)
{
  __shared__ unsigned hist[11 * THREADS];         // row 10 = pad row for v==1.0
  __shared__ unsigned red[10 * 16 * 3];
  __shared__ unsigned lastflag;
  const int t = threadIdx.x;
  #pragma unroll
  for (int s = 0; s < 11; ++s) hist[s * THREADS + t] = 0u;
  __syncthreads();

  const int blk   = blockIdx.x;
  const int plane = blk >> 4;                     // 0..95 (0..47 = x, 48..95 = y)
  const int sub   = blk & 15;
  const float* src = (plane < PLANES ? xin + (size_t)plane * PLANE_PX
                                     : yin + (size_t)(plane - PLANES) * PLANE_PX)
                   + (size_t)sub * CHUNK;
  const float4* src4 = (const float4*)src;
  unsigned* mycol = hist + t;

  constexpr int ITERS = CHUNK / (THREADS * 4);    // 16
  float4 c0 = src4[t];
  float4 c1 = src4[THREADS + t];
  #pragma unroll 4
  for (int it = 0; it < ITERS; ++it) {
    float4 cur = c0;
    c0 = c1;
    if (it + 2 < ITERS) c1 = src4[(it + 2) * THREADS + t];
    float vv[4] = {cur.x, cur.y, cur.z, cur.w};
    #pragma unroll
    for (int j = 0; j < 4; ++j) {
      float W  = vv[j] * 10.0f;                   // [0,10]
      unsigned k = (unsigned)W;                   // trunc; k=10 -> pad row
      float d  = W - floorf(W);                   // v_fract
      float mp = d - 0.5f;
      bool lo  = mp < 0.0f;
      float ex = __expf(fmaf(-15.0f, fabsf(mp), 7.5f));   // e^{15m-7.5}... = e^{7.5-15|mp|}
      float sg = __builtin_amdgcn_rcpf(1.0f + ex);        // sigma(-15m)
      float scale = lo ? -255.0f : 62.0f;
      int   qs = (int)(sg * scale);               // trunc toward 0
      unsigned sel = lo ? 18u : 7u;
      unsigned pk  = ((unsigned)qs << sel) + BASE;
      atomicAdd(&mycol[k << 8], pk);              // ds_add_u32, fire-and-forget
    }
  }
  __syncthreads();

  // stage 1: 160 threads, each sums 16 columns of one bin (unpacked fields)
  if (t < 160) {
    const int bin = t >> 4, grp = t & 15;
    const uint4* hp = (const uint4*)(hist + (bin << 8) + (grp << 4));
    unsigned sa = 0, sb = 0, sc = 0;
    #pragma unroll
    for (int q = 0; q < 4; ++q) {
      uint4 u4 = hp[q];
      unsigned uu[4] = {u4.x, u4.y, u4.z, u4.w};
      #pragma unroll
      for (int e = 0; e < 4; ++e) {
        unsigned u = uu[e];
        sa += u >> 18; sb += (u >> 7) & 0x7FFu; sc += u & 0x7Fu;
      }
    }
    const int base = (bin * 16 + grp) * 3;
    red[base] = sa; red[base + 1] = sb; red[base + 2] = sc;
  }
  __syncthreads();

  // stage 2: 30 threads -> global integer atomics (deterministic)
  if (t < 30) {
    const int bin = t / 3, c = t - 3 * bin;
    unsigned s = 0;
    #pragma unroll
    for (int g = 0; g < 16; ++g) s += red[(bin * 16 + g) * 3 + c];
    atomicAdd(&G[plane * 30 + bin * 3 + c], s);
  }
  __syncthreads();

  // fused loss: last block to increment the counter computes the scalar
  if (t == 0) {
    __threadfence();                              // release my G updates
    unsigned old = atomicAdd(&G[CTR], 1u);
    lastflag = (old == (unsigned)(NBLK - 1)) ? 1u : 0u;
  }
  __syncthreads();
  if (lastflag != 0u) {
    __threadfence();                              // acquire all G updates
    float val = 0.0f;
    for (int item = t; item < 480; item += THREADS) {
      const int pc = item / 10, i = item - pc * 10;
      const unsigned* gx = G + pc * 30;
      const unsigned* gy = G + (pc + PLANES) * 30;
      float hx = (float)gx[3 * i] * (1.0f / 255.0f)
               - (float)gx[3 * i + 1] * (1.0f / 62.0f)
               + (i > 0 ? (float)gx[3 * (i - 1) + 1] * (1.0f / 62.0f) : 0.0f)
               + (i < 9 ? (float)gx[3 * (i + 1) + 2]
                        - (float)gx[3 * (i + 1)] * (1.0f / 255.0f) : 0.0f);
      float hy = (float)gy[3 * i] * (1.0f / 255.0f)
               - (float)gy[3 * i + 1] * (1.0f / 62.0f)
               + (i > 0 ? (float)gy[3 * (i - 1) + 1] * (1.0f / 62.0f) : 0.0f)
               + (i < 9 ? (float)gy[3 * (i + 1) + 2]
                        - (float)gy[3 * (i + 1)] * (1.0f / 255.0f) : 0.0f);
      val += fabsf(hx - hy);
    }
    #pragma unroll
    for (int off = 32; off >= 1; off >>= 1) val += __shfl_xor(val, off, 64);
    float* fred = (float*)red;
    if ((t & 63) == 0) fred[t >> 6] = val;
    __syncthreads();
    if (t == 0)
      out[0] = (fred[0] + fred[1] + fred[2] + fred[3]) * 6.25e-7f;
  }
}

extern "C" void kernel_launch(void* const* d_in, const int* in_sizes, int n_in,
                              void* d_out, int out_size, void* d_ws, size_t ws_size,
                              hipStream_t stream) {
  const float* x = (const float*)d_in[0];
  const float* y = (const float*)d_in[1];
  unsigned* G = (unsigned*)d_ws;               // 2880 accum words + counter
  hipMemsetAsync(d_ws, 0, (CTR + 1) * sizeof(unsigned), stream);
  soft_hist_fused<<<NBLK, THREADS, 0, stream>>>(x, y, G, (float*)d_out);
}

// Round 12
// 31.780 us; speedup vs baseline: 2.3080x; 2.3080x over previous
//
#include <hip/hip_runtime.h>

// SoftHistLoss: x,y [16,3,512,512] f32 -> scalar f32
// hist_i = A[i] - B[i] + B[i-1] + (C[i+1] - A[i+1]); A=sum qa/255, B=sum qb/62,
// C=count, accumulated at bin k=floor(10v) as ONE packed ds_add_u32:
//   bits[31:18] qa  (col sum <= 64*255 = 16320 < 2^14)
//   bits[17: 7] qb  (col sum <= 64*31  = 1984  < 2^11)
//   bits[ 6: 0] 1   (col sum <= 64            < 2^7)
// Single-sigmoid form (R10): m = 0.5-|d-0.5|, s = sigma(-15m) = 1/(1+e^{15m}):
//   d<0.5: qa = 255-trunc(255s), qb=0;  d>=0.5: qa=255, qb=trunc(62s)
// -> pk = BASE + (trunc(s*scale) << sel), BASE=(255<<18)+1.
// R12: THREADS 256->512, SPP 16->8 => 768 blocks (3/CU, 24 waves/CU unchanged,
// 64 px/thread unchanged) - halves block prologue/epilogue/dispatch count to
// attack the ~14us in-kernel fixed cost inferred from R8's 2-pass probe.
// Lessons: no FP atomics on LDS (R2); no dependent LDS reads in pixel loop
// (R9); do NOT fuse cold epilogue into hot kernel - wrecks regalloc (R11).

static constexpr int PLANES   = 48;               // 16*3 per image
static constexpr int PLANE_PX = 512 * 512;
static constexpr int SPP      = 8;                // sub-blocks per plane
static constexpr int THREADS  = 512;
static constexpr int CHUNK    = PLANE_PX / SPP;   // 32768 px/block, 64 px/thread
static constexpr int NBLK     = 96 * SPP;         // 768 = 3 blocks/CU, one round
static constexpr unsigned BASE = (255u << 18) + 1u;

__global__ __launch_bounds__(THREADS, 6) void soft_hist_partial(
    const float* __restrict__ xin, const float* __restrict__ yin,
    unsigned* __restrict__ G /* [96][30] u32: per plane {A,B,C} x 10 bins */)
{
  __shared__ unsigned hist[11 * THREADS];         // 22528 B (row 10 = pad, v==1.0)
  __shared__ unsigned red[10 * 32 * 3];           // 3840 B
  const int t = threadIdx.x;
  #pragma unroll
  for (int s = 0; s < 11; ++s) hist[s * THREADS + t] = 0u;
  __syncthreads();

  const int blk   = blockIdx.x;
  const int plane = blk >> 3;                     // 0..95 (0..47 = x, 48..95 = y)
  const int sub   = blk & 7;
  const float* src = (plane < PLANES ? xin + (size_t)plane * PLANE_PX
                                     : yin + (size_t)(plane - PLANES) * PLANE_PX)
                   + (size_t)sub * CHUNK;
  const float4* src4 = (const float4*)src;
  unsigned* mycol = hist + t;

  constexpr int ITERS = CHUNK / (THREADS * 4);    // 16
  float4 c0 = src4[t];
  float4 c1 = src4[THREADS + t];
  #pragma unroll 4
  for (int it = 0; it < ITERS; ++it) {
    float4 cur = c0;
    c0 = c1;
    if (it + 2 < ITERS) c1 = src4[(it + 2) * THREADS + t];
    float vv[4] = {cur.x, cur.y, cur.z, cur.w};
    #pragma unroll
    for (int j = 0; j < 4; ++j) {
      float W  = vv[j] * 10.0f;                   // [0,10]
      unsigned k = (unsigned)W;                   // trunc; k=10 -> pad row
      float d  = W - floorf(W);                   // v_fract
      float mp = d - 0.5f;
      bool lo  = mp < 0.0f;
      float ex = __expf(fmaf(-15.0f, fabsf(mp), 7.5f));   // e^{7.5-15|mp|}
      float sg = __builtin_amdgcn_rcpf(1.0f + ex);        // sigma(-15m)
      float scale = lo ? -255.0f : 62.0f;
      int   qs = (int)(sg * scale);               // trunc toward 0
      unsigned sel = lo ? 18u : 7u;
      unsigned pk  = ((unsigned)qs << sel) + BASE;
      atomicAdd(&mycol[k * THREADS], pk);         // ds_add_u32, fire-and-forget
    }
  }
  __syncthreads();

  // stage 1: 320 threads, each sums 16 columns of one bin (unpacked fields)
  if (t < 320) {
    const int bin = t >> 5, grp = t & 31;         // 32 groups x 16 cols = 512
    const uint4* hp = (const uint4*)(hist + bin * THREADS + (grp << 4));
    unsigned sa = 0, sb = 0, sc = 0;
    #pragma unroll
    for (int q = 0; q < 4; ++q) {
      uint4 u4 = hp[q];
      unsigned uu[4] = {u4.x, u4.y, u4.z, u4.w};
      #pragma unroll
      for (int e = 0; e < 4; ++e) {
        unsigned u = uu[e];
        sa += u >> 18; sb += (u >> 7) & 0x7FFu; sc += u & 0x7Fu;
      }
    }
    const int base = (bin * 32 + grp) * 3;
    red[base] = sa; red[base + 1] = sb; red[base + 2] = sc;
  }
  __syncthreads();

  // stage 2: 30 threads -> global integer atomics (deterministic)
  if (t < 30) {
    const int bin = t / 3, c = t - 3 * bin;
    unsigned s = 0;
    #pragma unroll
    for (int g = 0; g < 32; ++g) s += red[(bin * 32 + g) * 3 + c];
    atomicAdd(&G[plane * 30 + bin * 3 + c], s);
  }
}

__global__ __launch_bounds__(512) void soft_hist_loss(
    const unsigned* __restrict__ G, float* __restrict__ out)
{
  __shared__ float wred[8];
  const int t = threadIdx.x;
  float val = 0.0f;
  if (t < 480) {
    const int pc = t / 10;        // (batch,channel) 0..47
    const int i  = t - pc * 10;   // bin
    const unsigned* gx = G + pc * 30;
    const unsigned* gy = G + (pc + PLANES) * 30;
    // hist_i = A[i]/255 - B[i]/62 + B[i-1]/62 + C[i+1] - A[i+1]/255
    float hx = (float)gx[3 * i] * (1.0f / 255.0f)
             - (float)gx[3 * i + 1] * (1.0f / 62.0f)
             + (i > 0 ? (float)gx[3 * (i - 1) + 1] * (1.0f / 62.0f) : 0.0f)
             + (i < 9 ? (float)gx[3 * (i + 1) + 2]
                      - (float)gx[3 * (i + 1)] * (1.0f / 255.0f) : 0.0f);
    float hy = (float)gy[3 * i] * (1.0f / 255.0f)
             - (float)gy[3 * i + 1] * (1.0f / 62.0f)
             + (i > 0 ? (float)gy[3 * (i - 1) + 1] * (1.0f / 62.0f) : 0.0f)
             + (i < 9 ? (float)gy[3 * (i + 1) + 2]
                      - (float)gy[3 * (i + 1)] * (1.0f / 255.0f) : 0.0f);
    val = fabsf(hx - hy);
  }
  #pragma unroll
  for (int off = 32; off >= 1; off >>= 1) val += __shfl_xor(val, off, 64);
  if ((t & 63) == 0) wred[t >> 6] = val;
  __syncthreads();
  if (t == 0) {
    float s = 0.0f;
    #pragma unroll
    for (int w = 0; w < 8; ++w) s += wred[w];
    // loss = sum * (1/BINS) * (1/B) * 1e-4
    out[0] = s * 6.25e-7f;
  }
}

extern "C" void kernel_launch(void* const* d_in, const int* in_sizes, int n_in,
                              void* d_out, int out_size, void* d_ws, size_t ws_size,
                              hipStream_t stream) {
  const float* x = (const float*)d_in[0];
  const float* y = (const float*)d_in[1];
  unsigned* G = (unsigned*)d_ws;               // 96*30*4 = 11520 B
  hipMemsetAsync(d_ws, 0, 96 * 30 * sizeof(unsigned), stream);
  soft_hist_partial<<<NBLK, THREADS, 0, stream>>>(x, y, G);
  soft_hist_loss<<<1, 512, 0, stream>>>(G, (float*)d_out);
}